// Round 1
// 610.247 us; speedup vs baseline: 1.2670x; 1.2670x over previous
//
#include <hip/hip_runtime.h>
#include <hip/hip_bf16.h>

// DecodeLSTM: B=8192, T=1, H=1024, L=4.  fp32 containers (bf16-rounded values).
// T=1 => layers 1..3: z = h @ (Wx+Wh) + b ; layer 0: z = h0@Wh0 + x*Wx0 + b0.
// R5: 256x256 8-wave deep-pipelined GEMM (T2 swizzle + T3/T4 counted vmcnt +
//     T5 setprio), double-buffered 128 KiB LDS, fused LSTM epilogue.

#define MB_  8192
#define HB_  1024
#define KB_  1024

typedef __attribute__((ext_vector_type(8))) short bf16x8;
typedef __attribute__((ext_vector_type(4))) float f32x4;

#define BAR()  asm volatile("s_barrier" ::: "memory")
#define VMW(n) asm volatile("s_waitcnt vmcnt(" #n ")" ::: "memory")

__device__ __forceinline__ void load_lds16(const void* g, void* l) {
  __builtin_amdgcn_global_load_lds(
      (const __attribute__((address_space(1))) unsigned int*)g,
      (__attribute__((address_space(3))) unsigned int*)l, 16, 0, 0);
}

__device__ __forceinline__ float sigmoidf_(float x) { return 1.0f / (1.0f + __expf(-x)); }
__device__ __forceinline__ float tanhf_fast(float x) { return 2.0f / (1.0f + __expf(-2.0f * x)) - 1.0f; }

__device__ __forceinline__ short f2bf(float f) {
  __hip_bfloat16 h = __float2bfloat16(f);
  return *(short*)&h;
}

// ---------------------------------------------------------------------------
// fp32 -> bf16 bulk convert (for h0). 8 elements/thread.
// ---------------------------------------------------------------------------
__global__ __launch_bounds__(256) void cvt_f32_bf16(
    const float* __restrict__ in, __hip_bfloat16* __restrict__ out)
{
  const int i = blockIdx.x * 256 + threadIdx.x;
  const float4 f0 = ((const float4*)in)[i * 2];
  const float4 f1 = ((const float4*)in)[i * 2 + 1];
  bf16x8 v;
  v[0] = f2bf(f0.x); v[1] = f2bf(f0.y); v[2] = f2bf(f0.z); v[3] = f2bf(f0.w);
  v[4] = f2bf(f1.x); v[5] = f2bf(f1.y); v[6] = f2bf(f1.z); v[7] = f2bf(f1.w);
  ((bf16x8*)out)[i] = v;
}

// ---------------------------------------------------------------------------
// Weight prep: WT[L][n][k] bf16  (L=0: Wh0^T ; L>0: (Wx[L-1]+Wh[L-1])^T)
// ---------------------------------------------------------------------------
__global__ __launch_bounds__(256) void prep_weights(
    const float* __restrict__ Wh0,
    const float* __restrict__ Wx,
    const float* __restrict__ Wh,
    __hip_bfloat16* __restrict__ WT)
{
  __shared__ float t[32][33];
  const int L  = blockIdx.z;
  const int n0 = blockIdx.x * 32;
  const int k0 = blockIdx.y * 32;
  const int tx = threadIdx.x & 31;
  const int ty = threadIdx.x >> 5;   // 0..7
  if (L == 0) {
    for (int kk = ty; kk < 32; kk += 8)
      t[kk][tx] = Wh0[(size_t)(k0 + kk) * 4096 + n0 + tx];
  } else {
    const float* wx = Wx + (size_t)(L - 1) * 1024 * 4096;
    const float* wh = Wh + (size_t)(L - 1) * 1024 * 4096;
    for (int kk = ty; kk < 32; kk += 8) {
      size_t idx = (size_t)(k0 + kk) * 4096 + n0 + tx;
      t[kk][tx] = wx[idx] + wh[idx];
    }
  }
  __syncthreads();
  __hip_bfloat16* dst = WT + (size_t)L * 4096 * 1024;
  for (int nn = ty; nn < 32; nn += 8)
    dst[(size_t)(n0 + nn) * 1024 + k0 + tx] = __float2bfloat16(t[tx][nn]);
}

// ---------------------------------------------------------------------------
// Fused LSTM layer, 256x256 tile (64 h-cols x 4 gates), BK=64, 8 waves (2Mx4N).
// LDS: 2 K-tile buffers x (A 32K + B 32K) = 128 KiB.  Each buffer: halftiles
//   A0 A1 B0 B1 of 16 KiB (128 rows x 64 bf16).
// Swizzle (T2): LDS[row*128 + x] holds global col-byte (x ^ ((row&7)<<4));
//   linear global_load_lds dest + pre-swizzled global source + swizzled reads.
// Schedule per K-tile (4 phases): p0 [vmcnt(2);bar; issue A0,A1(t+1); q(s0,g0)]
//   bar; p1 [issue B0(t+1); q(s1,g0)]; p2 [vmcnt(6);bar; issue B1(t+1);
//   q(s0,g1)]; bar; p3 [q(s1,g1)].  vmcnt never 0 in steady loop (T4).
// C/D map: n-col=lane&15, m-row=(lane>>4)*4+reg (verified in prior kernel).
// ---------------------------------------------------------------------------
template<bool FIRST, bool LAST>
__global__ __launch_bounds__(512, 2) void lstm_layer_kernel(
    const __hip_bfloat16* __restrict__ A,     // [8192][1024] bf16
    const __hip_bfloat16* __restrict__ WT,    // [4096][1024] bf16 (pre-summed)
    const float*          __restrict__ bias,  // [4096] fp32
    const float*                       cin,   // [8192][1024] fp32
    float*                             cout,  // may alias cin (same positions)
    const float*          __restrict__ xvec,  // layer0 x [8192] fp32
    const float*          __restrict__ Wx0,   // layer0 [4096] fp32
    void*                 __restrict__ hout)  // LAST? fp32 : bf16
{
  __shared__ __align__(16) char lds[131072];

  const int tid  = threadIdx.x;
  const int lane = tid & 63;
  const int wv   = tid >> 6;          // 0..7
  const int wr   = wv & 1;            // M-half of wave
  const int wc   = wv >> 1;           // 0..3: 16-h-col group
  const int l15  = lane & 15;
  const int lq   = lane >> 4;         // 0..3
  const int sw   = (l15 & 7) << 4;    // read-side XOR swizzle

  // bijective XCD swizzle (512 % 8 == 0)
  const int bid = blockIdx.x;
  const int sz  = (bid & 7) * 64 + (bid >> 3);
  const int m0  = (sz >> 4) * 256;    // 32 m-tiles
  const int n0h = (sz & 15) * 64;     // 16 n-tiles (h-cols)

  // staging source byte-offsets (global), pre-swizzled: col ^= (row&7)<<4
  unsigned aoff[2][2], boff[2][2];
#pragma unroll
  for (int h = 0; h < 2; ++h)
#pragma unroll
    for (int j = 0; j < 2; ++j) {
      const int c    = j * 512 + tid;          // chunk 0..1023 of halftile
      const int row  = c >> 3;                 // 0..127
      const int colb = ((c & 7) ^ (row & 7)) << 4;
      aoff[h][j] = (unsigned)((m0 + h * 128 + row) * 2048 + colb);
      const int grow = (h * 2 + (row >> 6)) * 1024 + n0h + (row & 63);
      boff[h][j] = (unsigned)(grow * 2048 + colb);
    }
  const int ldsu = wv * 1024;         // wave-uniform LDS chunk base (bytes)
  const char* Ab = (const char*)A;
  const char* Wb = (const char*)WT;

  f32x4 acc[8][4] = {};               // [m-frag 0..7][gate 0..3]

  auto stageA = [&](int h, int kt, int b) {
#pragma unroll
    for (int j = 0; j < 2; ++j)
      load_lds16(Ab + aoff[h][j] + kt * 128,
                 lds + b * 65536 + h * 16384 + j * 8192 + ldsu);
  };
  auto stageB = [&](int h, int kt, int b) {
#pragma unroll
    for (int j = 0; j < 2; ++j)
      load_lds16(Wb + boff[h][j] + kt * 128,
                 lds + b * 65536 + 32768 + h * 16384 + j * 8192 + ldsu);
  };
  // one C-quadrant (s-half sh, gate-half gh) x K=64: 12 ds_read_b128, 16 MFMA
  auto quad = [&](int b, int sh, int gh) {
    const char* bA = lds + b * 65536 + wr * 16384;
    const char* bB = lds + b * 65536 + 32768 + gh * 16384;
    bf16x8 af[4][2], bfr[2][2];
#pragma unroll
    for (int i = 0; i < 4; ++i) {
      const int rl = (sh * 4 + i) * 16 + l15;
#pragma unroll
      for (int ks = 0; ks < 2; ++ks)
        af[i][ks] = *(const bf16x8*)(bA + rl * 128 + ((ks * 64 + lq * 16) ^ sw));
    }
#pragma unroll
    for (int g = 0; g < 2; ++g) {
      const int rb = g * 64 + wc * 16 + l15;
#pragma unroll
      for (int ks = 0; ks < 2; ++ks)
        bfr[g][ks] = *(const bf16x8*)(bB + rb * 128 + ((ks * 64 + lq * 16) ^ sw));
    }
    __builtin_amdgcn_s_setprio(1);
#pragma unroll
    for (int i = 0; i < 4; ++i)
#pragma unroll
      for (int g = 0; g < 2; ++g)
#pragma unroll
        for (int ks = 0; ks < 2; ++ks)
          acc[sh * 4 + i][gh * 2 + g] = __builtin_amdgcn_mfma_f32_16x16x32_bf16(
              af[i][ks], bfr[g][ks], acc[sh * 4 + i][gh * 2 + g], 0, 0, 0);
    __builtin_amdgcn_s_setprio(0);
  };

  // prologue: K-tile 0 -> buf0 (issue order A0 A1 B0 B1 = vmcnt accounting)
  stageA(0, 0, 0); stageA(1, 0, 0); stageB(0, 0, 0); stageB(1, 0, 0);

  for (int t = 0; t < 15; ++t) {
    const int cur = t & 1, nxt = cur ^ 1;
    VMW(2); BAR();                     // tile t: A0,A1,B0 landed (B1 may fly)
    stageA(0, t + 1, nxt); stageA(1, t + 1, nxt);
    quad(cur, 0, 0);
    BAR();
    stageB(0, t + 1, nxt);
    quad(cur, 1, 0);
    VMW(6); BAR();                     // tile t: B1 landed
    stageB(1, t + 1, nxt);
    quad(cur, 0, 1);
    BAR();
    quad(cur, 1, 1);
  }
  // peeled final K-tile (t=15, buf1): no staging; only here vmcnt drains to 0
  VMW(2); BAR();
  quad(1, 0, 0);
  quad(1, 1, 0);
  VMW(0); BAR();
  quad(1, 0, 1);
  quad(1, 1, 1);

  // ---- epilogue ----
  BAR();                               // all LDS frag-reads complete
  float* sC = (float*)lds;             // [256][64] fp32 c tile (64 KiB)
  float* sH = (float*)(lds + 65536);   // [256][64] fp32 h tile (64 KiB)

  // cin tile (rows m0..+255, h-cols n0h..+63) -> sC, coalesced async, linear
#pragma unroll
  for (int j = 0; j < 8; ++j) {
    const int idx = j * 512 + tid;
    const int row = idx >> 4;
    const int c4  = (idx & 15) << 2;
    load_lds16(cin + (size_t)(m0 + row) * HB_ + n0h + c4,
               (char*)sC + j * 8192 + ldsu);
  }

  const int jj  = n0h + wc * 16 + l15;  // global h-col of this thread
  const float bi  = bias[0 * HB_ + jj];
  const float bf_ = bias[1 * HB_ + jj];
  const float bg  = bias[2 * HB_ + jj];
  const float bo  = bias[3 * HB_ + jj];
  float wxi = 0.f, wxf = 0.f, wxg = 0.f, wxo = 0.f;
  if (FIRST) {
    wxi = Wx0[0 * HB_ + jj];
    wxf = Wx0[1 * HB_ + jj];
    wxg = Wx0[2 * HB_ + jj];
    wxo = Wx0[3 * HB_ + jj];
  }
  VMW(0); BAR();                       // cin tile landed

  const int hl = wc * 16 + l15;        // local h-col 0..63
#pragma unroll
  for (int s = 0; s < 8; ++s) {
#pragma unroll
    for (int r = 0; r < 4; ++r) {
      const int mloc = wr * 128 + s * 16 + (lq << 2) + r;  // local row 0..255
      float zi = acc[s][0][r] + bi;
      float zf = acc[s][1][r] + bf_;
      float zg = acc[s][2][r] + bg;
      float zo = acc[s][3][r] + bo;
      if (FIRST) {
        const float xv = xvec[m0 + mloc];
        zi += xv * wxi; zf += xv * wxf; zg += xv * wxg; zo += xv * wxo;
      }
      const float ig = sigmoidf_(zi);
      const float fg = sigmoidf_(zf);
      const float gg = tanhf_fast(zg);
      const float og = sigmoidf_(zo);
      const float cn = fg * sC[mloc * 64 + hl] + ig * gg;  // 1 owner per elem
      const float hn = og * tanhf_fast(cn);
      sC[mloc * 64 + hl] = cn;
      sH[mloc * 64 + hl] = hn;
    }
  }
  BAR();                               // c/h tiles complete

  // coalesced stores: c (fp32) 256x64 -> float4, 8 passes
#pragma unroll
  for (int p = 0; p < 8; ++p) {
    const int idx = p * 512 + tid;
    const int row = idx >> 4, seg = idx & 15;
    *(float4*)(cout + (size_t)(m0 + row) * HB_ + n0h + seg * 4) =
        *(const float4*)&sC[row * 64 + seg * 4];
  }
  if (LAST) {
#pragma unroll
    for (int p = 0; p < 8; ++p) {
      const int idx = p * 512 + tid;
      const int row = idx >> 4, seg = idx & 15;
      *(float4*)((float*)hout + (size_t)(m0 + row) * HB_ + n0h + seg * 4) =
          *(const float4*)&sH[row * 64 + seg * 4];
    }
  } else {
#pragma unroll
    for (int p = 0; p < 4; ++p) {
      const int idx = p * 512 + tid;
      const int row = idx >> 3, seg = idx & 7;             // 8 bf16 per thread
      const float4 f0 = *(const float4*)&sH[row * 64 + seg * 8];
      const float4 f1 = *(const float4*)&sH[row * 64 + seg * 8 + 4];
      bf16x8 v;
      v[0] = f2bf(f0.x); v[1] = f2bf(f0.y); v[2] = f2bf(f0.z); v[3] = f2bf(f0.w);
      v[4] = f2bf(f1.x); v[5] = f2bf(f1.y); v[6] = f2bf(f1.z); v[7] = f2bf(f1.w);
      *(bf16x8*)((__hip_bfloat16*)hout + (size_t)(m0 + row) * HB_ + n0h + seg * 8) = v;
    }
  }
}

// ---------------------------------------------------------------------------
// Head: x_pred[b] = sum_k h4[b,k]*Wd[k] + bd.  One wave per row. All fp32.
// ---------------------------------------------------------------------------
__global__ __launch_bounds__(256) void head_kernel(
    const float* __restrict__ h,
    const float* __restrict__ Wd,
    const float* __restrict__ bd,
    float* __restrict__ xpred)
{
  const int row  = blockIdx.x * 4 + (threadIdx.x >> 6);
  const int lane = threadIdx.x & 63;
  const float* hr = h + (size_t)row * HB_;
  float s = 0.f;
#pragma unroll
  for (int t = 0; t < 16; ++t) {
    const int k = t * 64 + lane;
    s += hr[k] * Wd[k];
  }
#pragma unroll
  for (int off = 32; off; off >>= 1) s += __shfl_down(s, off, 64);
  if (lane == 0) xpred[row] = s + bd[0];
}

// ---------------------------------------------------------------------------
extern "C" void kernel_launch(void* const* d_in, const int* in_sizes, int n_in,
                              void* d_out, int out_size, void* d_ws, size_t ws_size,
                              hipStream_t stream) {
  (void)in_sizes; (void)n_in; (void)out_size; (void)ws_size;
  const float* x   = (const float*)d_in[0];
  const float* c0  = (const float*)d_in[1];
  const float* h0  = (const float*)d_in[2];
  const float* Wx0 = (const float*)d_in[3];
  const float* Wh0 = (const float*)d_in[4];
  const float* b0  = (const float*)d_in[5];
  const float* Wx  = (const float*)d_in[6];
  const float* Wh  = (const float*)d_in[7];
  const float* b   = (const float*)d_in[8];
  const float* Wd  = (const float*)d_in[9];
  const float* bd  = (const float*)d_in[10];

  float* out_c = (float*)d_out;
  float* out_h = out_c + (size_t)MB_ * HB_;
  float* out_x = out_h + (size_t)MB_ * HB_;

  char* ws = (char*)d_ws;
  __hip_bfloat16* WT = (__hip_bfloat16*)ws;                       // 32 MiB
  __hip_bfloat16* hA = (__hip_bfloat16*)(ws + (size_t)33554432);  // 16 MiB
  __hip_bfloat16* hB = (__hip_bfloat16*)(ws + (size_t)50331648);  // 16 MiB

  const size_t WTL = (size_t)4096 * 1024;

  prep_weights<<<dim3(128, 32, 4), 256, 0, stream>>>(Wh0, Wx, Wh, WT);
  cvt_f32_bf16<<<4096, 256, 0, stream>>>(h0, hA);   // h0 -> bf16 (exact)

  // L0: A=hA(h0 bf16), c: c0 -> out_c ; h1 -> hB
  lstm_layer_kernel<true,  false><<<512, 512, 0, stream>>>(
      hA, WT, b0, c0, out_c, x, Wx0, hB);
  // L1: A=hB ; c in-place out_c ; h2 -> hA
  lstm_layer_kernel<false, false><<<512, 512, 0, stream>>>(
      hB, WT + 1 * WTL, b + 0 * 4096, out_c, out_c, nullptr, nullptr, hA);
  // L2: A=hA ; c in-place ; h3 -> hB
  lstm_layer_kernel<false, false><<<512, 512, 0, stream>>>(
      hA, WT + 2 * WTL, b + 1 * 4096, out_c, out_c, nullptr, nullptr, hB);
  // L3: A=hB ; c in-place (final) ; h4 -> out_h (fp32)
  lstm_layer_kernel<false, true><<<512, 512, 0, stream>>>(
      hB, WT + 3 * WTL, b + 2 * 4096, out_c, out_c, nullptr, nullptr, out_h);

  head_kernel<<<2048, 256, 0, stream>>>(out_h, Wd, bd, out_x);
}

// Round 2
// 578.683 us; speedup vs baseline: 1.3361x; 1.0545x over previous
//
#include <hip/hip_runtime.h>
#include <hip/hip_bf16.h>

// DecodeLSTM: B=8192, T=1, H=1024, L=4.  fp32 containers (bf16-rounded values).
// T=1 => layers 1..3: z = h @ (Wx+Wh) + b ; layer 0: z = h0@Wh0 + x*Wx0 + b0.
// R6: single-read frag schedule (24 ds_read_b128/K-tile, frags held in regs),
//     counted vmcnt(2)/(4), n-major XCD mapping (B L2-resident per XCD),
//     cin prefetch overlapped with final K-tile.

#define MB_  8192
#define HB_  1024
#define KB_  1024

typedef __attribute__((ext_vector_type(8))) short bf16x8;
typedef __attribute__((ext_vector_type(4))) float f32x4;

#define BAR()  asm volatile("s_barrier" ::: "memory")
#define VMW(n) asm volatile("s_waitcnt vmcnt(" #n ")" ::: "memory")

__device__ __forceinline__ void load_lds16(const void* g, void* l) {
  __builtin_amdgcn_global_load_lds(
      (const __attribute__((address_space(1))) unsigned int*)g,
      (__attribute__((address_space(3))) unsigned int*)l, 16, 0, 0);
}

__device__ __forceinline__ float sigmoidf_(float x) { return 1.0f / (1.0f + __expf(-x)); }
__device__ __forceinline__ float tanhf_fast(float x) { return 2.0f / (1.0f + __expf(-2.0f * x)) - 1.0f; }

__device__ __forceinline__ short f2bf(float f) {
  __hip_bfloat16 h = __float2bfloat16(f);
  return *(short*)&h;
}

// ---------------------------------------------------------------------------
// fp32 -> bf16 bulk convert (for h0). 8 elements/thread.
// ---------------------------------------------------------------------------
__global__ __launch_bounds__(256) void cvt_f32_bf16(
    const float* __restrict__ in, __hip_bfloat16* __restrict__ out)
{
  const int i = blockIdx.x * 256 + threadIdx.x;
  const float4 f0 = ((const float4*)in)[i * 2];
  const float4 f1 = ((const float4*)in)[i * 2 + 1];
  bf16x8 v;
  v[0] = f2bf(f0.x); v[1] = f2bf(f0.y); v[2] = f2bf(f0.z); v[3] = f2bf(f0.w);
  v[4] = f2bf(f1.x); v[5] = f2bf(f1.y); v[6] = f2bf(f1.z); v[7] = f2bf(f1.w);
  ((bf16x8*)out)[i] = v;
}

// ---------------------------------------------------------------------------
// Weight prep: WT[L][n][k] bf16  (L=0: Wh0^T ; L>0: (Wx[L-1]+Wh[L-1])^T)
// ---------------------------------------------------------------------------
__global__ __launch_bounds__(256) void prep_weights(
    const float* __restrict__ Wh0,
    const float* __restrict__ Wx,
    const float* __restrict__ Wh,
    __hip_bfloat16* __restrict__ WT)
{
  __shared__ float t[32][33];
  const int L  = blockIdx.z;
  const int n0 = blockIdx.x * 32;
  const int k0 = blockIdx.y * 32;
  const int tx = threadIdx.x & 31;
  const int ty = threadIdx.x >> 5;   // 0..7
  if (L == 0) {
    for (int kk = ty; kk < 32; kk += 8)
      t[kk][tx] = Wh0[(size_t)(k0 + kk) * 4096 + n0 + tx];
  } else {
    const float* wx = Wx + (size_t)(L - 1) * 1024 * 4096;
    const float* wh = Wh + (size_t)(L - 1) * 1024 * 4096;
    for (int kk = ty; kk < 32; kk += 8) {
      size_t idx = (size_t)(k0 + kk) * 4096 + n0 + tx;
      t[kk][tx] = wx[idx] + wh[idx];
    }
  }
  __syncthreads();
  __hip_bfloat16* dst = WT + (size_t)L * 4096 * 1024;
  for (int nn = ty; nn < 32; nn += 8)
    dst[(size_t)(n0 + nn) * 1024 + k0 + tx] = __float2bfloat16(t[tx][nn]);
}

// ---------------------------------------------------------------------------
// Fused LSTM layer, 256x256 tile (64 h-cols x 4 gates), BK=64, 8 waves (2Mx4N).
// LDS: 2 K-tile buffers x (A 32K + B 32K) = 128 KiB.  Each buffer: halftiles
//   A0 A1 B0 B1 of 16 KiB (128 rows x 64 bf16).
// Swizzle (T2): LDS[row*128 + x] holds global col-byte (x ^ ((row&7)<<4));
//   linear global_load_lds dest + pre-swizzled global source + swizzled reads.
// Per K-tile (4 quadrant phases, each frag read ONCE, held in regs):
//   ph0: VMW(2);BAR; issue A(t+1); read A(s0-3)+B(g0,1); BAR; 16 MFMA
//   ph1: VMW(4);BAR; issue B0(t+1); read B(g2,3);        BAR; 16 MFMA
//   ph2:             issue B1(t+1); read A(s4-7);        BAR; 16 MFMA
//   ph3:                                                 BAR; 16 MFMA
// vmcnt never 0 in the main loop (T4). cin prefetch overlaps final K-tile.
// n-major block map: XCD x owns n-tiles {2x,2x+1} -> B panel L2-resident.
// C/D map: n-col=lane&15, m-row=(lane>>4)*4+reg (verified in prior kernel).
// ---------------------------------------------------------------------------
template<bool FIRST, bool LAST>
__global__ __launch_bounds__(512, 2) void lstm_layer_kernel(
    const __hip_bfloat16* __restrict__ A,     // [8192][1024] bf16
    const __hip_bfloat16* __restrict__ WT,    // [4096][1024] bf16 (pre-summed)
    const float*          __restrict__ bias,  // [4096] fp32
    const float*                       cin,   // [8192][1024] fp32
    float*                             cout,  // may alias cin (same positions)
    const float*          __restrict__ xvec,  // layer0 x [8192] fp32
    const float*          __restrict__ Wx0,   // layer0 [4096] fp32
    void*                 __restrict__ hout)  // LAST? fp32 : bf16
{
  __shared__ __align__(16) char lds[131072];

  const int tid  = threadIdx.x;
  const int lane = tid & 63;
  const int wv   = tid >> 6;          // 0..7
  const int wr   = wv & 1;            // M-half of wave
  const int wc   = wv >> 1;           // 0..3: 16-h-col group
  const int l15  = lane & 15;
  const int lq   = lane >> 4;         // 0..3
  const int sw   = (l15 & 7) << 4;    // read-side XOR swizzle

  // bijective XCD swizzle, n-major: XCD x gets sz in [64x,64x+64) ->
  // n-tiles {2x,2x+1} x all 32 m-tiles -> B working set/XCD = 512 KB (L2-fit)
  const int bid = blockIdx.x;
  const int sz  = (bid & 7) * 64 + (bid >> 3);
  const int m0  = (sz & 31) * 256;    // 32 m-tiles
  const int n0h = (sz >> 5) * 64;     // 16 n-tiles (h-cols)

  // staging source byte-offsets (global), pre-swizzled: col ^= (row&7)<<4
  unsigned aoff[2][2], boff[2][2];
#pragma unroll
  for (int h = 0; h < 2; ++h)
#pragma unroll
    for (int j = 0; j < 2; ++j) {
      const int c    = j * 512 + tid;          // chunk 0..1023 of halftile
      const int row  = c >> 3;                 // 0..127
      const int colb = ((c & 7) ^ (row & 7)) << 4;
      aoff[h][j] = (unsigned)((m0 + h * 128 + row) * 2048 + colb);
      const int grow = (h * 2 + (row >> 6)) * 1024 + n0h + (row & 63);
      boff[h][j] = (unsigned)(grow * 2048 + colb);
    }
  const int ldsu = wv * 1024;         // wave-uniform LDS chunk base (bytes)
  const char* Ab = (const char*)A;
  const char* Wb = (const char*)WT;

  f32x4 acc[8][4] = {};               // [m-frag 0..7][gate 0..3]
  bf16x8 Af[4][2];                    // current s-half frags (reused)
  bf16x8 Bf0[2][2], Bf1[2][2];        // gate-half frags, live whole K-tile

  auto stageA = [&](int h, int kt, int b) {
#pragma unroll
    for (int j = 0; j < 2; ++j)
      load_lds16(Ab + aoff[h][j] + kt * 128,
                 lds + b * 65536 + h * 16384 + j * 8192 + ldsu);
  };
  auto stageB = [&](int h, int kt, int b) {
#pragma unroll
    for (int j = 0; j < 2; ++j)
      load_lds16(Wb + boff[h][j] + kt * 128,
                 lds + b * 65536 + 32768 + h * 16384 + j * 8192 + ldsu);
  };
  auto readA = [&](const char* cb, int shalf) {      // 8 x ds_read_b128
    const char* bA = cb + wr * 16384;
#pragma unroll
    for (int i = 0; i < 4; ++i) {
      const int rl = (shalf * 4 + i) * 16 + l15;
#pragma unroll
      for (int ks = 0; ks < 2; ++ks)
        Af[i][ks] = *(const bf16x8*)(bA + rl * 128 + ((ks * 64 + lq * 16) ^ sw));
    }
  };
  auto readB = [&](const char* cb, int ghalf, bf16x8 Bf[2][2]) {  // 4 reads
    const char* bB = cb + 32768 + ghalf * 16384;
#pragma unroll
    for (int g = 0; g < 2; ++g) {
      const int rb = g * 64 + wc * 16 + l15;
#pragma unroll
      for (int ks = 0; ks < 2; ++ks)
        Bf[g][ks] = *(const bf16x8*)(bB + rb * 128 + ((ks * 64 + lq * 16) ^ sw));
    }
  };

#define MFMA16(SH, GH, BF)                                                    \
  do {                                                                        \
    __builtin_amdgcn_s_setprio(1);                                            \
    _Pragma("unroll")                                                         \
    for (int i_ = 0; i_ < 4; ++i_)                                            \
      _Pragma("unroll")                                                       \
      for (int g_ = 0; g_ < 2; ++g_)                                          \
        _Pragma("unroll")                                                     \
        for (int ks_ = 0; ks_ < 2; ++ks_)                                     \
          acc[(SH) * 4 + i_][(GH) * 2 + g_] =                                 \
              __builtin_amdgcn_mfma_f32_16x16x32_bf16(                        \
                  Af[i_][ks_], BF[g_][ks_], acc[(SH) * 4 + i_][(GH) * 2 + g_],\
                  0, 0, 0);                                                   \
    __builtin_amdgcn_s_setprio(0);                                            \
  } while (0)

  // prologue: K-tile 0 -> buf0 (issue order A0 A1 B0 B1 = vmcnt accounting)
  stageA(0, 0, 0); stageA(1, 0, 0); stageB(0, 0, 0); stageB(1, 0, 0);

  for (int t = 0; t < 15; ++t) {
    const int cur = t & 1, nxt = cur ^ 1;
    const char* cb = lds + cur * 65536;
    // ph0 --- needs A(cur), B0(cur); leaves B1(cur) in flight
    VMW(2); BAR();
    stageA(0, t + 1, nxt); stageA(1, t + 1, nxt);   // +4 -> 6
    readA(cb, 0);
    readB(cb, 0, Bf0);
    BAR(); MFMA16(0, 0, Bf0);
    // ph1 --- needs B1(cur)
    VMW(4); BAR();                                   // drain B1(cur): 6 -> 4
    stageB(0, t + 1, nxt);                           // +2 -> 6
    readB(cb, 1, Bf1);
    BAR(); MFMA16(0, 1, Bf1);
    // ph2
    stageB(1, t + 1, nxt);                           // +2 -> 8
    readA(cb, 1);
    BAR(); MFMA16(1, 1, Bf1);
    // ph3 --- Bf0 still live in regs
    BAR(); MFMA16(1, 0, Bf0);
  }

  // peeled final K-tile (t=15, buf1): no weight staging; cin prefetch here.
  float* sC = (float*)lds;             // [256][64] fp32 c tile (buf0, 64 KiB)
  float* sH = (float*)(lds + 65536);   // [256][64] fp32 h tile (buf1, 64 KiB)
  {
    const char* cb = lds + 65536;
    VMW(2); BAR();                     // A,B0 landed; B1 (2) in flight
    // cin tile (rows m0..+255, h-cols n0h..+63) -> buf0, coalesced async
#pragma unroll
    for (int j = 0; j < 8; ++j) {
      const int idx = j * 512 + tid;
      const int row = idx >> 4;
      const int c4  = (idx & 15) << 2;
      load_lds16(cin + (size_t)(m0 + row) * HB_ + n0h + c4,
                 (char*)sC + j * 8192 + ldsu);       // +8 -> 10
    }
    readA(cb, 0);
    readB(cb, 0, Bf0);
    BAR(); MFMA16(0, 0, Bf0);
    VMW(8); BAR();                     // drain B1: 10 -> 8 (cin still flying)
    readB(cb, 1, Bf1);
    BAR(); MFMA16(0, 1, Bf1);
    readA(cb, 1);
    BAR(); MFMA16(1, 1, Bf1);
    BAR(); MFMA16(1, 0, Bf0);
  }

  // ---- epilogue ----
  const int jj  = n0h + wc * 16 + l15;  // global h-col of this thread
  const float bi  = bias[0 * HB_ + jj];
  const float bf_ = bias[1 * HB_ + jj];
  const float bg  = bias[2 * HB_ + jj];
  const float bo  = bias[3 * HB_ + jj];
  float wxi = 0.f, wxf = 0.f, wxg = 0.f, wxo = 0.f;
  if (FIRST) {
    wxi = Wx0[0 * HB_ + jj];
    wxf = Wx0[1 * HB_ + jj];
    wxg = Wx0[2 * HB_ + jj];
    wxo = Wx0[3 * HB_ + jj];
  }
  VMW(0); BAR();                       // cin tile landed (all waves)

  const int hl = wc * 16 + l15;        // local h-col 0..63
#pragma unroll
  for (int s = 0; s < 8; ++s) {
#pragma unroll
    for (int r = 0; r < 4; ++r) {
      const int mloc = wr * 128 + s * 16 + (lq << 2) + r;  // local row 0..255
      float zi = acc[s][0][r] + bi;
      float zf = acc[s][1][r] + bf_;
      float zg = acc[s][2][r] + bg;
      float zo = acc[s][3][r] + bo;
      if (FIRST) {
        const float xv = xvec[m0 + mloc];
        zi += xv * wxi; zf += xv * wxf; zg += xv * wxg; zo += xv * wxo;
      }
      const float ig = sigmoidf_(zi);
      const float fg = sigmoidf_(zf);
      const float gg = tanhf_fast(zg);
      const float og = sigmoidf_(zo);
      const float cn = fg * sC[mloc * 64 + hl] + ig * gg;  // 1 owner per elem
      const float hn = og * tanhf_fast(cn);
      sC[mloc * 64 + hl] = cn;
      sH[mloc * 64 + hl] = hn;
    }
  }
  BAR();                               // c/h tiles complete

  // coalesced stores: c (fp32) 256x64 -> float4, 8 passes
#pragma unroll
  for (int p = 0; p < 8; ++p) {
    const int idx = p * 512 + tid;
    const int row = idx >> 4, seg = idx & 15;
    *(float4*)(cout + (size_t)(m0 + row) * HB_ + n0h + seg * 4) =
        *(const float4*)&sC[row * 64 + seg * 4];
  }
  if (LAST) {
#pragma unroll
    for (int p = 0; p < 8; ++p) {
      const int idx = p * 512 + tid;
      const int row = idx >> 4, seg = idx & 15;
      *(float4*)((float*)hout + (size_t)(m0 + row) * HB_ + n0h + seg * 4) =
          *(const float4*)&sH[row * 64 + seg * 4];
    }
  } else {
#pragma unroll
    for (int p = 0; p < 4; ++p) {
      const int idx = p * 512 + tid;
      const int row = idx >> 3, seg = idx & 7;             // 8 bf16 per thread
      const float4 f0 = *(const float4*)&sH[row * 64 + seg * 8];
      const float4 f1 = *(const float4*)&sH[row * 64 + seg * 8 + 4];
      bf16x8 v;
      v[0] = f2bf(f0.x); v[1] = f2bf(f0.y); v[2] = f2bf(f0.z); v[3] = f2bf(f0.w);
      v[4] = f2bf(f1.x); v[5] = f2bf(f1.y); v[6] = f2bf(f1.z); v[7] = f2bf(f1.w);
      *(bf16x8*)((__hip_bfloat16*)hout + (size_t)(m0 + row) * HB_ + n0h + seg * 8) = v;
    }
  }
#undef MFMA16
}

// ---------------------------------------------------------------------------
// Head: x_pred[b] = sum_k h4[b,k]*Wd[k] + bd.  One wave per row. All fp32.
// ---------------------------------------------------------------------------
__global__ __launch_bounds__(256) void head_kernel(
    const float* __restrict__ h,
    const float* __restrict__ Wd,
    const float* __restrict__ bd,
    float* __restrict__ xpred)
{
  const int row  = blockIdx.x * 4 + (threadIdx.x >> 6);
  const int lane = threadIdx.x & 63;
  const float* hr = h + (size_t)row * HB_;
  float s = 0.f;
#pragma unroll
  for (int t = 0; t < 16; ++t) {
    const int k = t * 64 + lane;
    s += hr[k] * Wd[k];
  }
#pragma unroll
  for (int off = 32; off; off >>= 1) s += __shfl_down(s, off, 64);
  if (lane == 0) xpred[row] = s + bd[0];
}

// ---------------------------------------------------------------------------
extern "C" void kernel_launch(void* const* d_in, const int* in_sizes, int n_in,
                              void* d_out, int out_size, void* d_ws, size_t ws_size,
                              hipStream_t stream) {
  (void)in_sizes; (void)n_in; (void)out_size; (void)ws_size;
  const float* x   = (const float*)d_in[0];
  const float* c0  = (const float*)d_in[1];
  const float* h0  = (const float*)d_in[2];
  const float* Wx0 = (const float*)d_in[3];
  const float* Wh0 = (const float*)d_in[4];
  const float* b0  = (const float*)d_in[5];
  const float* Wx  = (const float*)d_in[6];
  const float* Wh  = (const float*)d_in[7];
  const float* b   = (const float*)d_in[8];
  const float* Wd  = (const float*)d_in[9];
  const float* bd  = (const float*)d_in[10];

  float* out_c = (float*)d_out;
  float* out_h = out_c + (size_t)MB_ * HB_;
  float* out_x = out_h + (size_t)MB_ * HB_;

  char* ws = (char*)d_ws;
  __hip_bfloat16* WT = (__hip_bfloat16*)ws;                       // 32 MiB
  __hip_bfloat16* hA = (__hip_bfloat16*)(ws + (size_t)33554432);  // 16 MiB
  __hip_bfloat16* hB = (__hip_bfloat16*)(ws + (size_t)50331648);  // 16 MiB

  const size_t WTL = (size_t)4096 * 1024;

  prep_weights<<<dim3(128, 32, 4), 256, 0, stream>>>(Wh0, Wx, Wh, WT);
  cvt_f32_bf16<<<4096, 256, 0, stream>>>(h0, hA);   // h0 -> bf16 (exact)

  // L0: A=hA(h0 bf16), c: c0 -> out_c ; h1 -> hB
  lstm_layer_kernel<true,  false><<<512, 512, 0, stream>>>(
      hA, WT, b0, c0, out_c, x, Wx0, hB);
  // L1: A=hB ; c in-place out_c ; h2 -> hA
  lstm_layer_kernel<false, false><<<512, 512, 0, stream>>>(
      hB, WT + 1 * WTL, b + 0 * 4096, out_c, out_c, nullptr, nullptr, hA);
  // L2: A=hA ; c in-place ; h3 -> hB
  lstm_layer_kernel<false, false><<<512, 512, 0, stream>>>(
      hA, WT + 2 * WTL, b + 1 * 4096, out_c, out_c, nullptr, nullptr, hB);
  // L3: A=hB ; c in-place (final) ; h4 -> out_h (fp32)
  lstm_layer_kernel<false, true><<<512, 512, 0, stream>>>(
      hB, WT + 3 * WTL, b + 2 * 4096, out_c, out_c, nullptr, nullptr, out_h);

  head_kernel<<<2048, 256, 0, stream>>>(out_h, Wd, bd, out_x);
}